// Round 8
// baseline (6147.828 us; speedup 1.0000x reference)
//
#include <hip/hip_runtime.h>
#include <hip/hip_bf16.h>
#include <stdint.h>

#define Tn 512
#define Bn 64
#define Hn 512
#define LDP 520           // LDS row pitch (u16): 1040B
#define NWG 128
#define NTHR 512

typedef unsigned short u16;
typedef unsigned int u32;
typedef unsigned long long u64;
typedef __attribute__((ext_vector_type(8))) short bf16x8;
typedef __attribute__((ext_vector_type(4))) float f32x4;

// ws layout (bytes):
//   0     : slots[128] (one 64B line per WG)                8KB
//   8192  : go[128]    (one 64B line per WG)                8KB
//   16384 : h0buf [2][Bn][Hn] bf16 (128KB)
//   147456: h1buf [2][Bn][Hn] bf16 (128KB)
//   278528: xbf [Tn][Bn][Hn] bf16 (32MB), if xok
#define GO_OFF   2048      // u32 index
#define HBUF_OFF 16384     // bytes

__device__ __forceinline__ u16 f2bf(float f) {
  u32 u = __float_as_uint(f);
  u = (u + 0x7FFFu + ((u >> 16) & 1u)) >> 16;   // RNE
  return (u16)u;
}
__device__ __forceinline__ float sigf(float x) { return 1.f / (1.f + __expf(-x)); }
__device__ __forceinline__ float mytanh(float x) {
  float e = __expf(2.f * x);
  return 1.f - 2.f / (e + 1.f);
}

// ---------- pre-kernel: x -> bf16 into ws, hx -> h parity-1 buffers ----------
extern "C" __global__ void __launch_bounds__(256)
lstm_prep(const float* __restrict__ x, const float* __restrict__ hx,
          u32* __restrict__ ws, int xok) {
  u16* h0buf = (u16*)((char*)ws + HBUF_OFF);
  u16* h1buf = h0buf + 2 * Bn * Hn;
  u16* xbf   = h1buf + 2 * Bn * Hn;
  const int gt = blockIdx.x * 256 + threadIdx.x;   // 0..524287
  if (xok) {
#pragma unroll
    for (int i = 0; i < 8; ++i) {
      const int c = gt + (i << 19);                // float4 chunk id, 4194304 total
      const float4 v = *(const float4*)(x + (size_t)c * 4);
      const u64 pk = (u64)((u32)f2bf(v.x) | ((u32)f2bf(v.y) << 16)) |
                     ((u64)((u32)f2bf(v.z) | ((u32)f2bf(v.w) << 16)) << 32);
      *(u64*)(xbf + (size_t)c * 4) = pk;
    }
  }
  if (gt < 32768) {
    const int e0 = 2 * gt;
    const int l = e0 >> 15;
    const int off = e0 & 32767;
    const u32 pk = (u32)f2bf(hx[e0]) | ((u32)f2bf(hx[e0 + 1]) << 16);
    *(u32*)((l ? h1buf : h0buf) + Bn * Hn + off) = pk;
  }
}

// ---------- main persistent cooperative kernel ----------
extern "C" __global__ void __launch_bounds__(NTHR, 1)
lstm_fused(const float* __restrict__ x, const float* __restrict__ hx,
           const float* __restrict__ cx, const float* __restrict__ Wih,
           const float* __restrict__ Whh, const float* __restrict__ bih,
           const float* __restrict__ bhh, float* __restrict__ out,
           u32* __restrict__ ws, int xok) {
  __shared__ u16 sh_inp[32 * LDP];

  const int wg = blockIdx.x;
  const int tid = threadIdx.x;
  const int layer = wg >> 6;        // 0..1
  const int rem = wg & 63;
  const int shalf = rem >> 5;       // batch half: samples 0-31 / 32-63
  const int cc = rem & 31;          // 16-column chunk
  const int wave = tid >> 6;        // 0..7
  const int lane = tid & 63;
  const int l15 = lane & 15;
  const int lhi = lane >> 4;
  const int mt = wave >> 1;         // 0..3 gate-row tile
  const int nt = wave & 1;          // 0..1 sample tile
  const bool leader_wg = (layer == 0) && (cc == 0);  // wg == shalf*32

  u32* slots = ws;                                   // slot[w] = slots[w*16]
  u32* gof   = ws + GO_OFF;                          // go[w]   = gof[w*16]
  u16* h0buf = (u16*)((char*)ws + HBUF_OFF);
  u16* h1buf = h0buf + 2 * Bn * Hn;
  u16* xbf   = h1buf + 2 * Bn * Hn;
  u16* hbuf_my = layer ? h1buf : h0buf;

  // ---- weights -> registers. WG rows (64): j = col*4 + gate, col base cc*16 ----
  const int jrow = mt * 16 + l15;
  const int gateA = jrow & 3, colA = jrow >> 2;
  const int growA = gateA * Hn + cc * 16 + colA;
  const float* wihp = Wih + ((size_t)layer * 4 * Hn + growA) * Hn;
  const float* whhp = Whh + ((size_t)layer * 4 * Hn + growA) * Hn;
  bf16x8 wih_f[16], whh_f[16];
#pragma unroll
  for (int kt = 0; kt < 16; ++kt) {
    const int k0 = kt * 32 + lhi * 8;
    const float4 va0 = *(const float4*)(wihp + k0);
    const float4 va1 = *(const float4*)(wihp + k0 + 4);
    const float4 vb0 = *(const float4*)(whhp + k0);
    const float4 vb1 = *(const float4*)(whhp + k0 + 4);
    bf16x8 a, b;
    a[0]=(short)f2bf(va0.x); a[1]=(short)f2bf(va0.y); a[2]=(short)f2bf(va0.z); a[3]=(short)f2bf(va0.w);
    a[4]=(short)f2bf(va1.x); a[5]=(short)f2bf(va1.y); a[6]=(short)f2bf(va1.z); a[7]=(short)f2bf(va1.w);
    b[0]=(short)f2bf(vb0.x); b[1]=(short)f2bf(vb0.y); b[2]=(short)f2bf(vb0.z); b[3]=(short)f2bf(vb0.w);
    b[4]=(short)f2bf(vb1.x); b[5]=(short)f2bf(vb1.y); b[6]=(short)f2bf(vb1.z); b[7]=(short)f2bf(vb1.w);
    wih_f[kt] = a; whh_f[kt] = b;
  }

  // ---- elementwise lane mapping: acc reg r == gate r for (sampE, colE) ----
  const int colE = cc * 16 + mt * 4 + lhi;
  const int sampE = shalf * 32 + nt * 16 + l15;   // also the B-frag sample row
  float bias[4];
#pragma unroll
  for (int r = 0; r < 4; ++r) {
    const int grow = r * Hn + cc * 16 + mt * 4 + lhi;
    bias[r] = bih[layer * 4 * Hn + grow] + bhh[layer * 4 * Hn + grow];
  }
  float c_cur = cx[((size_t)layer * Bn + sampE) * Hn + colE];

  // per-lane base for recurrent-h B-frags (u16 units), parity added per step
  const u16* hfrag_base = hbuf_my + (size_t)sampE * Hn + lhi * 8;

  // stage x(t) -> sh_inp (layer 0); plain loads, coherent via prep boundary
  auto stage_x = [&](int t) {
    if (xok) {
      const u16* ip = xbf + ((size_t)t * Bn + shalf * 32) * Hn;
#pragma unroll
      for (int i = 0; i < 4; ++i) {
        const int chunk = tid + i * 512;             // 2048 chunks of 8 bf16
        const int row = chunk >> 6, c0 = (chunk & 63) * 8;
        const uint4 v = *(const uint4*)(ip + (size_t)row * Hn + c0);
        *(uint4*)(&sh_inp[row * LDP + c0]) = v;
      }
    } else {
      const float* xp = x + ((size_t)t * Bn + shalf * 32) * Hn;
#pragma unroll
      for (int i = 0; i < 8; ++i) {
        const int chunk = tid + i * 512;             // 4096 chunks of 4 floats
        const int row = chunk >> 7, c0 = (chunk & 127) * 4;
        const float4 v = *(const float4*)(xp + (size_t)row * Hn + c0);
        const u32 p0 = (u32)f2bf(v.x) | ((u32)f2bf(v.y) << 16);
        const u32 p1 = (u32)f2bf(v.z) | ((u32)f2bf(v.w) << 16);
        *(uint2*)(&sh_inp[row * LDP + c0]) = make_uint2(p0, p1);
      }
    }
  };
  if (layer == 0) stage_x(0);

  u32 ep = 0;
  for (int s = 0; s <= Tn; ++s) {
    const int t = layer ? s - 1 : s;
    const bool act = (t >= 0) && (t < Tn);

    // ---- issue recurrent-h B-frag loads straight to registers (LLC-direct) ----
    u64 q0[16], q1[16];
    if (act) {
      const u64* hp = (const u64*)(hfrag_base + (size_t)((t + 1) & 1) * Bn * Hn);
#pragma unroll
      for (int kt = 0; kt < 16; ++kt) {
        const u64* p = hp + kt * 8;                  // kt*32 u16 = kt*8 u64
        q0[kt] = __hip_atomic_load(p,     __ATOMIC_RELAXED, __HIP_MEMORY_SCOPE_AGENT);
        q1[kt] = __hip_atomic_load(p + 1, __ATOMIC_RELAXED, __HIP_MEMORY_SCOPE_AGENT);
      }
      // layer 1: restage h0(t) -> sh_inp (input operand)
      if (layer == 1) {
        const u16* ip = h0buf + (size_t)(t & 1) * Bn * Hn + (size_t)(shalf * 32) * Hn;
#pragma unroll
        for (int i = 0; i < 8; ++i) {
          const int chunk = tid + i * 512;           // 4096 chunks of 8B
          const int row = chunk >> 7, c0 = (chunk & 127) * 4;
          const u64 v = __hip_atomic_load((const u64*)(ip + (size_t)row * Hn + c0),
                                          __ATOMIC_RELAXED, __HIP_MEMORY_SCOPE_AGENT);
          *(u64*)(&sh_inp[row * LDP + c0]) = v;
        }
      }
    }
    __syncthreads();   // joins: L1 restage writes; L0 shadow-staged sh_inp from prev loop

    float hn = 0.f, cn = 0.f;
    if (act) {
      f32x4 a0 = {0,0,0,0}, a1 = {0,0,0,0}, b0 = {0,0,0,0}, b1 = {0,0,0,0};
      const int brow = (nt * 16 + l15) * LDP;
#pragma unroll
      for (int kt = 0; kt < 16; kt += 2) {
        const bf16x8 bi0 = *(const bf16x8*)(&sh_inp[brow + kt * 32 + lhi * 8]);
        const bf16x8 bi1 = *(const bf16x8*)(&sh_inp[brow + (kt + 1) * 32 + lhi * 8]);
        union { bf16x8 v; u64 q[2]; } U0, U1;
        U0.q[0] = q0[kt];     U0.q[1] = q1[kt];
        U1.q[0] = q0[kt + 1]; U1.q[1] = q1[kt + 1];
        a0 = __builtin_amdgcn_mfma_f32_16x16x32_bf16(wih_f[kt], bi0, a0, 0, 0, 0);
        b0 = __builtin_amdgcn_mfma_f32_16x16x32_bf16(whh_f[kt], U0.v, b0, 0, 0, 0);
        a1 = __builtin_amdgcn_mfma_f32_16x16x32_bf16(wih_f[kt + 1], bi1, a1, 0, 0, 0);
        b1 = __builtin_amdgcn_mfma_f32_16x16x32_bf16(whh_f[kt + 1], U1.v, b1, 0, 0, 0);
      }
      const float gi = a0[0] + a1[0] + b0[0] + b1[0] + bias[0];
      const float gf = a0[1] + a1[1] + b0[1] + b1[1] + bias[1];
      const float gg = a0[2] + a1[2] + b0[2] + b1[2] + bias[2];
      const float go_ = a0[3] + a1[3] + b0[3] + b1[3] + bias[3];
      cn = sigf(gf) * c_cur + sigf(gi) * mytanh(gg);
      hn = sigf(go_) * mytanh(cn);
      c_cur = cn;

      // pack 4 cols (lhi 0..3, same sample) -> 8B agent store into h buffer
      const u32 hu = (u32)f2bf(hn);
      const u32 pair = hu | (__shfl_xor(hu, 16) << 16);
      const u32 hi2 = __shfl_xor(pair, 32);
      if (lhi == 0) {
        const u64 v8 = (u64)pair | ((u64)hi2 << 32);
        u16* wp = hbuf_my + (size_t)(t & 1) * Bn * Hn + (size_t)sampE * Hn + cc * 16 + mt * 4;
        __hip_atomic_store((u64*)wp, v8, __ATOMIC_RELAXED, __HIP_MEMORY_SCOPE_AGENT);
      }
    }
    // drain h stores, join WG, signal own slot (R5-proven producer protocol)
    asm volatile("s_waitcnt vmcnt(0)" ::: "memory");
    __syncthreads();
    ++ep;
    if (tid == 0)
      __hip_atomic_store(&slots[wg * 16], ep, __ATOMIC_RELAXED, __HIP_MEMORY_SCOPE_AGENT);

    // ---- shadow work (off the inter-WG critical path) ----
    if (act) {
      if (layer == 1)
        out[((size_t)t * Bn + sampE) * Hn + colE] = hn;
      if (t == Tn - 1) {
        out[(size_t)Tn * Bn * Hn + ((size_t)layer * Bn + sampE) * Hn + colE] = hn;
        out[(size_t)Tn * Bn * Hn + (size_t)2 * Bn * Hn + ((size_t)layer * Bn + sampE) * Hn + colE] = cn;
      }
    }
    if (layer == 0 && (s + 1) < Tn) stage_x(s + 1);

    if (s == Tn) break;   // nobody depends on the final barrier

    // ---- per-half two-level barrier (R5 semantics, single-wave leader) ----
    // half members: layer0 wgs [shalf*32, +31], layer1 wgs [64+shalf*32, +31]
    if (leader_wg && wave == 0) {
      const int pid = (lane < 32) ? (shalf * 32 + lane)
                                  : (64 + shalf * 32 + (lane - 32));
      while (true) {
        const u32 v = __hip_atomic_load(&slots[pid * 16], __ATOMIC_RELAXED,
                                        __HIP_MEMORY_SCOPE_AGENT);
        if (__all((int)(v >= ep))) break;
        __builtin_amdgcn_s_sleep(1);
      }
      __hip_atomic_store(&gof[pid * 16], ep, __ATOMIC_RELAXED, __HIP_MEMORY_SCOPE_AGENT);
      // leader wave proceeds directly (it IS the certifier)
    } else {
      while (__hip_atomic_load(&gof[wg * 16], __ATOMIC_RELAXED,
                               __HIP_MEMORY_SCOPE_AGENT) < ep)
        __builtin_amdgcn_s_sleep(2);
    }
    asm volatile("" ::: "memory");   // keep data loads after the poll
  }
}

extern "C" void kernel_launch(void* const* d_in, const int* in_sizes, int n_in,
                              void* d_out, int out_size, void* d_ws, size_t ws_size,
                              hipStream_t stream) {
  const float* x   = (const float*)d_in[0];
  const float* hx  = (const float*)d_in[1];
  const float* cx  = (const float*)d_in[2];
  const float* Wih = (const float*)d_in[3];
  const float* Whh = (const float*)d_in[4];
  const float* bih = (const float*)d_in[5];
  const float* bhh = (const float*)d_in[6];
  float* outp = (float*)d_out;
  u32* wsp = (u32*)d_ws;

  const size_t need = HBUF_OFF + (size_t)8 * Bn * Hn + (size_t)Tn * Bn * Hn * 2;
  int xok = (ws_size >= need) ? 1 : 0;

  hipMemsetAsync(d_ws, 0, HBUF_OFF, stream);   // zero slot + go lines every call

  lstm_prep<<<dim3(2048), dim3(256), 0, stream>>>(x, hx, wsp, xok);

  void* args[] = {(void*)&x, (void*)&hx, (void*)&cx, (void*)&Wih, (void*)&Whh,
                  (void*)&bih, (void*)&bhh, (void*)&outp, (void*)&wsp, (void*)&xok};
  hipError_t e = hipLaunchCooperativeKernel((const void*)lstm_fused, dim3(NWG),
                                            dim3(NTHR), args, 0, stream);
  if (e != hipSuccess) {
    lstm_fused<<<dim3(NWG), dim3(NTHR), 0, stream>>>(x, hx, cx, Wih, Whh, bih, bhh, outp, wsp, xok);
  }
}

// Round 9
// 3048.437 us; speedup vs baseline: 2.0167x; 2.0167x over previous
//
#include <hip/hip_runtime.h>
#include <hip/hip_bf16.h>
#include <stdint.h>

#define Tn 512
#define Bn 64
#define Hn 512
#define LDP 520           // LDS row pitch (u16): 1040B
#define NWG 128
#define NTHR 512

typedef unsigned short u16;
typedef unsigned int u32;
typedef unsigned long long u64;
typedef __attribute__((ext_vector_type(8))) short bf16x8;
typedef __attribute__((ext_vector_type(4))) float f32x4;

// ws layout (bytes):
//   0     : slots[128] (one 64B line per WG)                8KB
//   8192  : go[128]    (one 64B line per WG)                8KB
//   16384 : h0buf [2][Bn][Hn] bf16 (128KB)
//   147456: h1buf [2][Bn][Hn] bf16 (128KB)
//   278528: xbf [Tn][Bn][Hn] bf16 (32MB), if xok
#define GO_OFF   2048      // u32 index
#define HBUF_OFF 16384     // bytes

__device__ __forceinline__ u16 f2bf(float f) {
  u32 u = __float_as_uint(f);
  u = (u + 0x7FFFu + ((u >> 16) & 1u)) >> 16;   // RNE
  return (u16)u;
}
__device__ __forceinline__ float sigf(float x) { return 1.f / (1.f + __expf(-x)); }
__device__ __forceinline__ float mytanh(float x) {
  float e = __expf(2.f * x);
  return 1.f - 2.f / (e + 1.f);
}

// ---------- pre-kernel: x -> bf16 into ws, hx -> h parity-1 buffers ----------
extern "C" __global__ void __launch_bounds__(256)
lstm_prep(const float* __restrict__ x, const float* __restrict__ hx,
          u32* __restrict__ ws, int xok) {
  u16* h0buf = (u16*)((char*)ws + HBUF_OFF);
  u16* h1buf = h0buf + 2 * Bn * Hn;
  u16* xbf   = h1buf + 2 * Bn * Hn;
  const int gt = blockIdx.x * 256 + threadIdx.x;   // 0..524287
  if (xok) {
#pragma unroll
    for (int i = 0; i < 8; ++i) {
      const int c = gt + (i << 19);                // float4 chunk id, 4194304 total
      const float4 v = *(const float4*)(x + (size_t)c * 4);
      const u64 pk = (u64)((u32)f2bf(v.x) | ((u32)f2bf(v.y) << 16)) |
                     ((u64)((u32)f2bf(v.z) | ((u32)f2bf(v.w) << 16)) << 32);
      *(u64*)(xbf + (size_t)c * 4) = pk;
    }
  }
  if (gt < 32768) {
    const int e0 = 2 * gt;
    const int l = e0 >> 15;
    const int off = e0 & 32767;
    const u32 pk = (u32)f2bf(hx[e0]) | ((u32)f2bf(hx[e0 + 1]) << 16);
    *(u32*)((l ? h1buf : h0buf) + Bn * Hn + off) = pk;
  }
}

// ---------- main persistent cooperative kernel ----------
extern "C" __global__ void __launch_bounds__(NTHR, 2)
lstm_fused(const float* __restrict__ x, const float* __restrict__ hx,
           const float* __restrict__ cx, const float* __restrict__ Wih,
           const float* __restrict__ Whh, const float* __restrict__ bih,
           const float* __restrict__ bhh, float* __restrict__ out,
           u32* __restrict__ ws, int xok) {
  __shared__ u16 sh_inp[32 * LDP];
  __shared__ u16 sh_h[32 * LDP];

  const int wg = blockIdx.x;
  const int tid = threadIdx.x;
  const int layer = wg >> 6;        // 0..1
  const int rem = wg & 63;
  const int shalf = rem >> 5;       // batch half: samples 0-31 / 32-63
  const int cc = rem & 31;          // 16-column chunk
  const int wave = tid >> 6;        // 0..7
  const int lane = tid & 63;
  const int l15 = lane & 15;
  const int lhi = lane >> 4;
  const int mt = wave >> 1;         // 0..3 gate-row tile
  const int nt = wave & 1;          // 0..1 sample tile
  const bool leader_wg = (layer == 0) && (cc == 0);  // wg == shalf*32

  u32* slots = ws;                                   // slot[w] = slots[w*16]
  u32* gof   = ws + GO_OFF;                          // go[w]   = gof[w*16]
  u16* h0buf = (u16*)((char*)ws + HBUF_OFF);
  u16* h1buf = h0buf + 2 * Bn * Hn;
  u16* xbf   = h1buf + 2 * Bn * Hn;
  u16* hbuf_my = layer ? h1buf : h0buf;

  // ---- weights -> registers. WG rows (64): j = col*4 + gate, col base cc*16 ----
  const int jrow = mt * 16 + l15;
  const int gateA = jrow & 3, colA = jrow >> 2;
  const int growA = gateA * Hn + cc * 16 + colA;
  const float* wihp = Wih + ((size_t)layer * 4 * Hn + growA) * Hn;
  const float* whhp = Whh + ((size_t)layer * 4 * Hn + growA) * Hn;
  bf16x8 wih_f[16], whh_f[16];
#pragma unroll
  for (int kt = 0; kt < 16; ++kt) {
    const int k0 = kt * 32 + lhi * 8;
    const float4 va0 = *(const float4*)(wihp + k0);
    const float4 va1 = *(const float4*)(wihp + k0 + 4);
    const float4 vb0 = *(const float4*)(whhp + k0);
    const float4 vb1 = *(const float4*)(whhp + k0 + 4);
    bf16x8 a, b;
    a[0]=(short)f2bf(va0.x); a[1]=(short)f2bf(va0.y); a[2]=(short)f2bf(va0.z); a[3]=(short)f2bf(va0.w);
    a[4]=(short)f2bf(va1.x); a[5]=(short)f2bf(va1.y); a[6]=(short)f2bf(va1.z); a[7]=(short)f2bf(va1.w);
    b[0]=(short)f2bf(vb0.x); b[1]=(short)f2bf(vb0.y); b[2]=(short)f2bf(vb0.z); b[3]=(short)f2bf(vb0.w);
    b[4]=(short)f2bf(vb1.x); b[5]=(short)f2bf(vb1.y); b[6]=(short)f2bf(vb1.z); b[7]=(short)f2bf(vb1.w);
    wih_f[kt] = a; whh_f[kt] = b;
  }

  // ---- elementwise lane mapping: acc reg r == gate r for (sampE, colE) ----
  const int colE = cc * 16 + mt * 4 + lhi;
  const int sampE = shalf * 32 + nt * 16 + l15;
  float bias[4];
#pragma unroll
  for (int r = 0; r < 4; ++r) {
    const int grow = r * Hn + cc * 16 + mt * 4 + lhi;
    bias[r] = bih[layer * 4 * Hn + grow] + bhh[layer * 4 * Hn + grow];
  }
  float c_cur = cx[((size_t)layer * Bn + sampE) * Hn + colE];

  // stage x(t) -> sh_inp (layer 0); plain loads, coherent via prep boundary;
  // xbf is read-only -> may cache in L2 (no per-step invalidate in this design)
  auto stage_x = [&](int t) {
    if (xok) {
      const u16* ip = xbf + ((size_t)t * Bn + shalf * 32) * Hn;
#pragma unroll
      for (int i = 0; i < 4; ++i) {
        const int chunk = tid + i * 512;             // 2048 chunks of 8 bf16
        const int row = chunk >> 6, c0 = (chunk & 63) * 8;
        const uint4 v = *(const uint4*)(ip + (size_t)row * Hn + c0);
        *(uint4*)(&sh_inp[row * LDP + c0]) = v;
      }
    } else {
      const float* xp = x + ((size_t)t * Bn + shalf * 32) * Hn;
#pragma unroll
      for (int i = 0; i < 8; ++i) {
        const int chunk = tid + i * 512;             // 4096 chunks of 4 floats
        const int row = chunk >> 7, c0 = (chunk & 127) * 4;
        const float4 v = *(const float4*)(xp + (size_t)row * Hn + c0);
        const u32 p0 = (u32)f2bf(v.x) | ((u32)f2bf(v.y) << 16);
        const u32 p1 = (u32)f2bf(v.z) | ((u32)f2bf(v.w) << 16);
        *(uint2*)(&sh_inp[row * LDP + c0]) = make_uint2(p0, p1);
      }
    }
  };
  if (layer == 0) stage_x(0);

  u32 ep = 0;
  for (int s = 0; s <= Tn; ++s) {
    const int t = layer ? s - 1 : s;
    const bool act = (t >= 0) && (t < Tn);

    if (act) {
      // restage h via relaxed agent atomic loads (LLC-direct, coherent with the
      // producers' agent write-through stores; no cache invalidate needed)
      const u16* hp = hbuf_my + (size_t)((t + 1) & 1) * Bn * Hn + (size_t)(shalf * 32) * Hn;
#pragma unroll
      for (int i = 0; i < 8; ++i) {
        const int chunk = tid + i * 512;             // 4096 chunks of 8B
        const int row = chunk >> 7, c0 = (chunk & 127) * 4;
        const u64 v = __hip_atomic_load((const u64*)(hp + (size_t)row * Hn + c0),
                                        __ATOMIC_RELAXED, __HIP_MEMORY_SCOPE_AGENT);
        *(u64*)(&sh_h[row * LDP + c0]) = v;
      }
      if (layer == 1) {
        const u16* ip = h0buf + (size_t)(t & 1) * Bn * Hn + (size_t)(shalf * 32) * Hn;
#pragma unroll
        for (int i = 0; i < 8; ++i) {
          const int chunk = tid + i * 512;
          const int row = chunk >> 7, c0 = (chunk & 127) * 4;
          const u64 v = __hip_atomic_load((const u64*)(ip + (size_t)row * Hn + c0),
                                          __ATOMIC_RELAXED, __HIP_MEMORY_SCOPE_AGENT);
          *(u64*)(&sh_inp[row * LDP + c0]) = v;
        }
      }
    }
    __syncthreads();

    float hn = 0.f, cn = 0.f;
    if (act) {
      f32x4 a0 = {0,0,0,0}, a1 = {0,0,0,0}, b0 = {0,0,0,0}, b1 = {0,0,0,0};
      const int brow = (nt * 16 + l15) * LDP;
#pragma unroll
      for (int kt = 0; kt < 16; kt += 2) {
        const bf16x8 bi0 = *(const bf16x8*)(&sh_inp[brow + kt * 32 + lhi * 8]);
        const bf16x8 bh0 = *(const bf16x8*)(&sh_h[brow + kt * 32 + lhi * 8]);
        const bf16x8 bi1 = *(const bf16x8*)(&sh_inp[brow + (kt + 1) * 32 + lhi * 8]);
        const bf16x8 bh1 = *(const bf16x8*)(&sh_h[brow + (kt + 1) * 32 + lhi * 8]);
        a0 = __builtin_amdgcn_mfma_f32_16x16x32_bf16(wih_f[kt], bi0, a0, 0, 0, 0);
        b0 = __builtin_amdgcn_mfma_f32_16x16x32_bf16(whh_f[kt], bh0, b0, 0, 0, 0);
        a1 = __builtin_amdgcn_mfma_f32_16x16x32_bf16(wih_f[kt + 1], bi1, a1, 0, 0, 0);
        b1 = __builtin_amdgcn_mfma_f32_16x16x32_bf16(whh_f[kt + 1], bh1, b1, 0, 0, 0);
      }
      const float gi = a0[0] + a1[0] + b0[0] + b1[0] + bias[0];
      const float gf = a0[1] + a1[1] + b0[1] + b1[1] + bias[1];
      const float gg = a0[2] + a1[2] + b0[2] + b1[2] + bias[2];
      const float go_ = a0[3] + a1[3] + b0[3] + b1[3] + bias[3];
      cn = sigf(gf) * c_cur + sigf(gi) * mytanh(gg);
      hn = sigf(go_) * mytanh(cn);
      c_cur = cn;

      // pack 4 cols (lhi 0..3, same sample) -> 8B agent store into h buffer
      const u32 hu = (u32)f2bf(hn);
      const u32 pair = hu | (__shfl_xor(hu, 16) << 16);
      const u32 hi2 = __shfl_xor(pair, 32);
      if (lhi == 0) {
        const u64 v8 = (u64)pair | ((u64)hi2 << 32);
        u16* wp = hbuf_my + (size_t)(t & 1) * Bn * Hn + (size_t)sampE * Hn + cc * 16 + mt * 4;
        __hip_atomic_store((u64*)wp, v8, __ATOMIC_RELAXED, __HIP_MEMORY_SCOPE_AGENT);
      }
    }
    // drain h stores, join WG, signal own slot (R5/R8-proven producer protocol)
    asm volatile("s_waitcnt vmcnt(0)" ::: "memory");
    __syncthreads();
    ++ep;
    if (tid == 0)
      __hip_atomic_store(&slots[wg * 16], ep, __ATOMIC_RELAXED, __HIP_MEMORY_SCOPE_AGENT);

    // ---- shadow work (off the inter-WG critical path) ----
    if (act) {
      if (layer == 1)
        out[((size_t)t * Bn + sampE) * Hn + colE] = hn;
      if (t == Tn - 1) {
        out[(size_t)Tn * Bn * Hn + ((size_t)layer * Bn + sampE) * Hn + colE] = hn;
        out[(size_t)Tn * Bn * Hn + (size_t)2 * Bn * Hn + ((size_t)layer * Bn + sampE) * Hn + colE] = cn;
      }
    }
    if (layer == 0 && (s + 1) < Tn) stage_x(s + 1);

    if (s == Tn) break;   // nobody depends on the final barrier

    // ---- per-half two-level barrier (validated in R8's full timed run) ----
    // half members: layer0 wgs [shalf*32, +31], layer1 wgs [64+shalf*32, +31]
    if (leader_wg && wave == 0) {
      const int pid = (lane < 32) ? (shalf * 32 + lane)
                                  : (64 + shalf * 32 + (lane - 32));
      while (true) {
        const u32 v = __hip_atomic_load(&slots[pid * 16], __ATOMIC_RELAXED,
                                        __HIP_MEMORY_SCOPE_AGENT);
        if (__all((int)(v >= ep))) break;
        __builtin_amdgcn_s_sleep(1);
      }
      __hip_atomic_store(&gof[pid * 16], ep, __ATOMIC_RELAXED, __HIP_MEMORY_SCOPE_AGENT);
      // leader wave proceeds directly (it IS the certifier)
    } else {
      while (__hip_atomic_load(&gof[wg * 16], __ATOMIC_RELAXED,
                               __HIP_MEMORY_SCOPE_AGENT) < ep)
        __builtin_amdgcn_s_sleep(1);
    }
    asm volatile("" ::: "memory");   // keep data loads after the poll
  }
}

extern "C" void kernel_launch(void* const* d_in, const int* in_sizes, int n_in,
                              void* d_out, int out_size, void* d_ws, size_t ws_size,
                              hipStream_t stream) {
  const float* x   = (const float*)d_in[0];
  const float* hx  = (const float*)d_in[1];
  const float* cx  = (const float*)d_in[2];
  const float* Wih = (const float*)d_in[3];
  const float* Whh = (const float*)d_in[4];
  const float* bih = (const float*)d_in[5];
  const float* bhh = (const float*)d_in[6];
  float* outp = (float*)d_out;
  u32* wsp = (u32*)d_ws;

  const size_t need = HBUF_OFF + (size_t)8 * Bn * Hn + (size_t)Tn * Bn * Hn * 2;
  int xok = (ws_size >= need) ? 1 : 0;

  hipMemsetAsync(d_ws, 0, HBUF_OFF, stream);   // zero slot + go lines every call

  lstm_prep<<<dim3(2048), dim3(256), 0, stream>>>(x, hx, wsp, xok);

  void* args[] = {(void*)&x, (void*)&hx, (void*)&cx, (void*)&Wih, (void*)&Whh,
                  (void*)&bih, (void*)&bhh, (void*)&outp, (void*)&wsp, (void*)&xok};
  hipError_t e = hipLaunchCooperativeKernel((const void*)lstm_fused, dim3(NWG),
                                            dim3(NTHR), args, 0, stream);
  if (e != hipSuccess) {
    lstm_fused<<<dim3(NWG), dim3(NTHR), 0, stream>>>(x, hx, cx, Wih, Whh, bih, bhh, outp, wsp, xok);
  }
}